// Round 8
// baseline (514.659 us; speedup 1.0000x reference)
//
#include <hip/hip_runtime.h>
#include <hip/hip_bf16.h>
#include <hip/hip_cooperative_groups.h>

namespace cg = cooperative_groups;

#define D 512            // d_in == d_out == 512
#define NROWS 65536      // output rows
#define CAP 32           // per-row bucket capacity (Poisson mean 8; P(>32) ~ 1e-10)
#define OVFCAP 4096      // overflow spill capacity
#define GBLK 1024        // cooperative grid: 4 blocks/CU x 256 CUs

typedef float f32x4 __attribute__((ext_vector_type(4)));
typedef int   i32x4 __attribute__((ext_vector_type(4)));

// ---------- single fused cooperative kernel: zero+transpose | bucket | spmm ----------
__global__ __launch_bounds__(256, 4) void k_fused(
    const float* __restrict__ w,
    __hip_bfloat16* __restrict__ wt,
    const int* __restrict__ rows,
    const int* __restrict__ cols,
    const float* __restrict__ vals, int nnz,
    int* __restrict__ counts, uint2* __restrict__ bucket,
    int* __restrict__ ovf_cnt, uint4* __restrict__ ovf,
    const f32x4* __restrict__ bias4, f32x4* __restrict__ out)
{
    cg::grid_group grid = cg::this_grid();
    const int b = blockIdx.x, t = threadIdx.x, nb = gridDim.x;
    __shared__ float tile[32][33];

    // ---- Phase A: zero counts/ovf_cnt + transpose w -> bf16 wT ----
    for (int i = b * 256 + t; i < NROWS / 4; i += nb * 256) {
        i32x4 z = {0, 0, 0, 0};
        ((i32x4*)counts)[i] = z;
    }
    if (b == 0 && t == 0) *ovf_cnt = 0;
    for (int tb = b; tb < 256; tb += nb) {      // 256 transpose tiles (blocks 0..255)
        int bx = tb & 15, by = tb >> 4;
        int tx = t & 31, ty = t >> 5;           // 32 x 8
        for (int i = ty; i < 32; i += 8)
            tile[i][tx] = w[(by * 32 + i) * D + bx * 32 + tx];
        __syncthreads();
        for (int i = ty; i < 32; i += 8)
            wt[(bx * 32 + i) * D + by * 32 + tx] = __float2bfloat16(tile[tx][i]);
    }
    __threadfence();
    grid.sync();

    // ---- Phase B: bucket scatter (1 nnz per thread per stride) ----
    for (int i = b * 256 + t; i < nnz; i += nb * 256) {
        int r = rows[i];
        int c = cols[i];
        float v = vals[i];
        int pos = atomicAdd(&counts[r], 1);
        if (pos < CAP) {
            bucket[(size_t)r * CAP + pos] = make_uint2((unsigned)c, __float_as_uint(v));
        } else {
            int o = atomicAdd(ovf_cnt, 1);
            if (o < OVFCAP)
                ovf[o] = make_uint4((unsigned)r, (unsigned)c, __float_as_uint(v), 0u);
        }
    }
    __threadfence();
    grid.sync();

    // ---- Phase C: spmm, one wave per row, rows strided across all waves ----
    const uint4* wt4 = (const uint4*)wt;
    const int lane = t & 63;
    const int gw = (b * 256 + t) >> 6;          // global wave id
    const int nw = nb * 4;                      // total waves
    f32x4 bb0 = bias4[lane * 2];
    f32x4 bb1 = bias4[lane * 2 + 1];
    int novf = *ovf_cnt;                        // uniformly 0 in practice
    if (novf > OVFCAP) novf = OVFCAP;
    for (int row = gw; row < NROWS; row += nw) {
        f32x4 a0 = bb0, a1 = bb1;
        int cnt = counts[row];
        if (cnt > CAP) cnt = CAP;
        uint2 mypair = make_uint2(0u, 0u);
        if (lane < cnt) mypair = bucket[(size_t)row * CAP + lane];
        for (int s = 0; s < cnt; ++s) {
            unsigned c = (unsigned)__shfl((int)mypair.x, s);
            float v = __uint_as_float(__shfl((int)mypair.y, s));
            uint4 wb = wt4[(size_t)c * 64 + lane];
            f32x4 w0, w1;
            w0.x = __uint_as_float(wb.x << 16);
            w0.y = __uint_as_float(wb.x & 0xffff0000u);
            w0.z = __uint_as_float(wb.y << 16);
            w0.w = __uint_as_float(wb.y & 0xffff0000u);
            w1.x = __uint_as_float(wb.z << 16);
            w1.y = __uint_as_float(wb.z & 0xffff0000u);
            w1.z = __uint_as_float(wb.w << 16);
            w1.w = __uint_as_float(wb.w & 0xffff0000u);
            a0 += v * w0;
            a1 += v * w1;
        }
        if (novf > 0) {                         // rare spill path
            for (int e = 0; e < novf; ++e) {
                uint4 p = ovf[e];
                if ((int)p.x == row) {
                    float v = __uint_as_float(p.z);
                    uint4 wb = wt4[(size_t)p.y * 64 + lane];
                    f32x4 w0, w1;
                    w0.x = __uint_as_float(wb.x << 16);
                    w0.y = __uint_as_float(wb.x & 0xffff0000u);
                    w0.z = __uint_as_float(wb.y << 16);
                    w0.w = __uint_as_float(wb.y & 0xffff0000u);
                    w1.x = __uint_as_float(wb.z << 16);
                    w1.y = __uint_as_float(wb.z & 0xffff0000u);
                    w1.z = __uint_as_float(wb.w << 16);
                    w1.w = __uint_as_float(wb.w & 0xffff0000u);
                    a0 += v * w0;
                    a1 += v * w1;
                }
            }
        }
        f32x4* op = out + (size_t)row * (D / 4);
        op[lane * 2]     = a0;
        op[lane * 2 + 1] = a1;
    }
}

// ---------- fallback path (tiny workspace): init out with bias, atomic scatter ----------
__global__ void k_init_bias(const float* __restrict__ bias, float* __restrict__ out, int total) {
    int i = blockIdx.x * blockDim.x + threadIdx.x;
    if (i < total) out[i] = bias[i & (D - 1)];
}

__global__ void k_atomic_spmm(const int* __restrict__ rows, const int* __restrict__ cols,
                              const float* __restrict__ vals, int nnz,
                              const float* __restrict__ w, float* __restrict__ out) {
    int wid = (int)((blockIdx.x * blockDim.x + threadIdx.x) >> 6);
    if (wid >= nnz) return;
    int lane = threadIdx.x & 63;
    int r = rows[wid];
    int c = cols[wid];
    float v = vals[wid];
    float* op = out + (size_t)r * D + lane * 8;
#pragma unroll
    for (int k = 0; k < 8; ++k) {
        float wv = w[(size_t)(lane * 8 + k) * D + c];
        atomicAdd(&op[k], v * wv);
    }
}

extern "C" void kernel_launch(void* const* d_in, const int* in_sizes, int n_in,
                              void* d_out, int out_size, void* d_ws, size_t ws_size,
                              hipStream_t stream) {
    const int*   rows   = (const int*)d_in[0];
    const int*   cols   = (const int*)d_in[1];
    const float* vals   = (const float*)d_in[2];
    const float* weight = (const float*)d_in[3];
    const float* bias   = (const float*)d_in[4];
    float*       out    = (float*)d_out;
    int nnz = in_sizes[0];

    // workspace carve-out
    char* ws = (char*)d_ws;
    size_t off = 0;
    auto alloc = [&](size_t bytes) -> void* {
        off = (off + 255) & ~(size_t)255;
        void* p = ws + off;
        off += bytes;
        return p;
    };
    __hip_bfloat16* wT = (__hip_bfloat16*)alloc((size_t)D * D * sizeof(__hip_bfloat16)); // 512 KiB
    int*   counts  = (int*)  alloc((size_t)NROWS * sizeof(int));                // 256 KiB
    int*   ovf_cnt = (int*)  alloc(256);                                        // 1 int
    uint4* ovf     = (uint4*)alloc((size_t)OVFCAP * sizeof(uint4));             // 64 KiB
    uint2* bucket  = (uint2*)alloc((size_t)NROWS * CAP * sizeof(uint2));        // 16 MiB
    const size_t need_full = off;

    if (need_full <= ws_size) {
        // ---- single cooperative dispatch ----
        const f32x4* bias4 = (const f32x4*)bias;
        f32x4* out4 = (f32x4*)out;
        void* args[] = {
            (void*)&weight, (void*)&wT, (void*)&rows, (void*)&cols, (void*)&vals,
            (void*)&nnz, (void*)&counts, (void*)&bucket, (void*)&ovf_cnt, (void*)&ovf,
            (void*)&bias4, (void*)&out4
        };
        hipLaunchCooperativeKernel((void*)k_fused, dim3(GBLK), dim3(256), args, 0, stream);
    } else {
        // ---- atomic fallback, direct (strided) weight reads ----
        k_init_bias<<<(out_size + 255) / 256, 256, 0, stream>>>(bias, out, out_size);
        k_atomic_spmm<<<((size_t)nnz * 64 + 255) / 256, 256, 0, stream>>>(rows, cols, vals, nnz, weight, out);
    }
}

// Round 9
// 372.021 us; speedup vs baseline: 1.3834x; 1.3834x over previous
//
#include <hip/hip_runtime.h>
#include <hip/hip_bf16.h>

#define D 512            // d_in == d_out == 512
#define NROWS 65536      // output rows
#define CAP 32           // per-row bucket capacity (Poisson mean 8; P(>32) ~ 1e-10)
#define OVFCAP 4096      // overflow spill capacity

typedef float f32x4 __attribute__((ext_vector_type(4)));
typedef int   i32x4 __attribute__((ext_vector_type(4)));

// ---------- zero counts + ovf_cnt (fast, precedes bucket) ----------
__global__ __launch_bounds__(256) void k_zero(int* __restrict__ counts,
                                              int* __restrict__ ovf_cnt) {
    int i = blockIdx.x * 256 + threadIdx.x;
    i32x4 z = {0, 0, 0, 0};
    ((i32x4*)counts)[i] = z;
    if (i == 0) *ovf_cnt = 0;
}

// ---------- fused: transpose w -> bf16 wT (blocks 0..255) + bucket scatter (blocks 256..) ----------
__global__ __launch_bounds__(256) void k_bucket(const float* __restrict__ w,
                                                __hip_bfloat16* __restrict__ wt,
                                                const int* __restrict__ rows,
                                                const int* __restrict__ cols,
                                                const float* __restrict__ vals, int nnz,
                                                int* __restrict__ counts, uint2* __restrict__ bucket,
                                                int* __restrict__ ovf_cnt, uint4* __restrict__ ovf) {
    int b = blockIdx.x;
    int t = threadIdx.x;
    if (b < 256) {
        // transpose tile: 16x16 grid of 32x32 tiles
        __shared__ float tile[32][33];
        int bx = b & 15, by = b >> 4;
        int tx = t & 31, ty = t >> 5;   // 32 x 8
        for (int i = ty; i < 32; i += 8)
            tile[i][tx] = __builtin_nontemporal_load(&w[(by * 32 + i) * D + bx * 32 + tx]);
        __syncthreads();
        for (int i = ty; i < 32; i += 8)
            wt[(bx * 32 + i) * D + by * 32 + tx] = __float2bfloat16(tile[tx][i]);
        return;
    }
    int i = (b - 256) * 256 + t;        // 1 nnz per thread
    if (i >= nnz) return;
    int r = __builtin_nontemporal_load(&rows[i]);
    int c = __builtin_nontemporal_load(&cols[i]);
    float v = __builtin_nontemporal_load(&vals[i]);
    int pos = atomicAdd(&counts[r], 1);
    if (pos < CAP) {
        bucket[(size_t)r * CAP + pos] = make_uint2((unsigned)c, __float_as_uint(v));
    } else {
        int o = atomicAdd(ovf_cnt, 1);
        if (o < OVFCAP)
            ovf[o] = make_uint4((unsigned)r, (unsigned)c, __float_as_uint(v), 0u);
    }
}

// ---------- main compute: one wave (64 lanes) per output row, bf16 weight gather; inline overflow fix ----------
__global__ __launch_bounds__(256) void k_spmm(const int* __restrict__ counts,
                                              const uint2* __restrict__ bucket,
                                              const uint4* __restrict__ wt4,   // bf16 wT, 64 uint4/row
                                              const f32x4* __restrict__ bias4,
                                              f32x4* __restrict__ out,
                                              const int* __restrict__ ovf_cnt,
                                              const uint4* __restrict__ ovf) {
    int wid = (int)((blockIdx.x * blockDim.x + threadIdx.x) >> 6);  // = row
    int lane = threadIdx.x & 63;
    f32x4 a0 = bias4[lane * 2];
    f32x4 a1 = bias4[lane * 2 + 1];
    int cnt = counts[wid];
    int novf = *ovf_cnt;                 // uniformly 0 in practice (broadcast load)
    if (cnt > CAP) cnt = CAP;
    // preload this row's pairs: lane i holds pair i (one coalesced load)
    uint2 mypair = make_uint2(0u, 0u);
    if (lane < cnt) mypair = bucket[(size_t)wid * CAP + lane];
    for (int s = 0; s < cnt; ++s) {
        unsigned c = (unsigned)__shfl((int)mypair.x, s);
        float v = __uint_as_float(__shfl((int)mypair.y, s));
        uint4 wb = wt4[(size_t)c * 64 + lane];
        f32x4 w0, w1;
        w0.x = __uint_as_float(wb.x << 16);
        w0.y = __uint_as_float(wb.x & 0xffff0000u);
        w0.z = __uint_as_float(wb.y << 16);
        w0.w = __uint_as_float(wb.y & 0xffff0000u);
        w1.x = __uint_as_float(wb.z << 16);
        w1.y = __uint_as_float(wb.z & 0xffff0000u);
        w1.z = __uint_as_float(wb.w << 16);
        w1.w = __uint_as_float(wb.w & 0xffff0000u);
        a0 += v * w0;
        a1 += v * w1;
    }
    if (novf > 0) {                      // rare path: scan spill list for this row
        if (novf > OVFCAP) novf = OVFCAP;
        for (int e = 0; e < novf; ++e) {
            uint4 p = ovf[e];
            if ((int)p.x == wid) {
                float v = __uint_as_float(p.z);
                uint4 wb = wt4[(size_t)p.y * 64 + lane];
                f32x4 w0, w1;
                w0.x = __uint_as_float(wb.x << 16);
                w0.y = __uint_as_float(wb.x & 0xffff0000u);
                w0.z = __uint_as_float(wb.y << 16);
                w0.w = __uint_as_float(wb.y & 0xffff0000u);
                w1.x = __uint_as_float(wb.z << 16);
                w1.y = __uint_as_float(wb.z & 0xffff0000u);
                w1.z = __uint_as_float(wb.w << 16);
                w1.w = __uint_as_float(wb.w & 0xffff0000u);
                a0 += v * w0;
                a1 += v * w1;
            }
        }
    }
    f32x4* op = out + (size_t)wid * (D / 4);
    op[lane * 2]     = a0;
    op[lane * 2 + 1] = a1;
}

// ---------- fallback path (tiny workspace): init out with bias, atomic scatter ----------
__global__ void k_init_bias(const float* __restrict__ bias, float* __restrict__ out, int total) {
    int i = blockIdx.x * blockDim.x + threadIdx.x;
    if (i < total) out[i] = bias[i & (D - 1)];
}

__global__ void k_atomic_spmm(const int* __restrict__ rows, const int* __restrict__ cols,
                              const float* __restrict__ vals, int nnz,
                              const float* __restrict__ w, float* __restrict__ out) {
    int wid = (int)((blockIdx.x * blockDim.x + threadIdx.x) >> 6);
    if (wid >= nnz) return;
    int lane = threadIdx.x & 63;
    int r = rows[wid];
    int c = cols[wid];
    float v = vals[wid];
    float* op = out + (size_t)r * D + lane * 8;
#pragma unroll
    for (int k = 0; k < 8; ++k) {
        float wv = w[(size_t)(lane * 8 + k) * D + c];
        atomicAdd(&op[k], v * wv);
    }
}

extern "C" void kernel_launch(void* const* d_in, const int* in_sizes, int n_in,
                              void* d_out, int out_size, void* d_ws, size_t ws_size,
                              hipStream_t stream) {
    const int*   rows   = (const int*)d_in[0];
    const int*   cols   = (const int*)d_in[1];
    const float* vals   = (const float*)d_in[2];
    const float* weight = (const float*)d_in[3];
    const float* bias   = (const float*)d_in[4];
    float*       out    = (float*)d_out;
    const int nnz = in_sizes[0];

    // workspace carve-out
    char* ws = (char*)d_ws;
    size_t off = 0;
    auto alloc = [&](size_t bytes) -> void* {
        off = (off + 255) & ~(size_t)255;
        void* p = ws + off;
        off += bytes;
        return p;
    };
    __hip_bfloat16* wT = (__hip_bfloat16*)alloc((size_t)D * D * sizeof(__hip_bfloat16)); // 512 KiB
    int*   counts  = (int*)  alloc((size_t)NROWS * sizeof(int));                // 256 KiB
    int*   ovf_cnt = (int*)  alloc(256);                                        // 1 int
    uint4* ovf     = (uint4*)alloc((size_t)OVFCAP * sizeof(uint4));             // 64 KiB
    uint2* bucket  = (uint2*)alloc((size_t)NROWS * CAP * sizeof(uint2));        // 16 MiB
    const size_t need_full = off;

    if (need_full <= ws_size) {
        // ---- DIAGNOSTIC ROUND: spmm launched 8x (idempotent) to amplify S in dur_us.
        //      dur = (Z+B) + 8*S; with R7's Z+B+S = 81.7 both terms resolve.
        const int nnzBlocks = (nnz + 255) / 256;
        k_zero<<<NROWS / 1024, 256, 0, stream>>>(counts, ovf_cnt);
        k_bucket<<<256 + nnzBlocks, 256, 0, stream>>>(weight, wT, rows, cols, vals, nnz,
                                                      counts, bucket, ovf_cnt, ovf);
        for (int rep = 0; rep < 8; ++rep) {
            k_spmm<<<NROWS / 4, 256, 0, stream>>>(counts, bucket, (const uint4*)wT,
                                                  (const f32x4*)bias, (f32x4*)out, ovf_cnt, ovf);
        }
    } else {
        // ---- atomic fallback, direct (strided) weight reads ----
        k_init_bias<<<(out_size + 255) / 256, 256, 0, stream>>>(bias, out, out_size);
        k_atomic_spmm<<<((size_t)nnz * 64 + 255) / 256, 256, 0, stream>>>(rows, cols, vals, nnz, weight, out);
    }
}

// Round 10
// 86.729 us; speedup vs baseline: 5.9341x; 4.2895x over previous
//
#include <hip/hip_runtime.h>
#include <hip/hip_bf16.h>

#define D 512            // d_in == d_out == 512
#define NROWS 65536      // output rows
#define CAP 32           // per-row bucket capacity (Poisson mean 8; P(>32) ~ 1e-10)
#define OVFCAP 4096      // overflow spill capacity

typedef float f32x4 __attribute__((ext_vector_type(4)));
typedef int   i32x4 __attribute__((ext_vector_type(4)));

// ---------- zero counts + ovf_cnt ----------
__global__ __launch_bounds__(256) void k_zero(int* __restrict__ counts,
                                              int* __restrict__ ovf_cnt) {
    int i = blockIdx.x * 256 + threadIdx.x;
    i32x4 z = {0, 0, 0, 0};
    ((i32x4*)counts)[i] = z;
    if (i == 0) *ovf_cnt = 0;
}

// ---------- fused: transpose (blocks 0..255) + bucket scatter, 2 nnz/thread, batched atomics ----------
__global__ __launch_bounds__(256) void k_bucket(const float* __restrict__ w,
                                                __hip_bfloat16* __restrict__ wt,
                                                const int* __restrict__ rows,
                                                const int* __restrict__ cols,
                                                const float* __restrict__ vals, int nnz,
                                                int* __restrict__ counts, uint2* __restrict__ bucket,
                                                int* __restrict__ ovf_cnt, uint4* __restrict__ ovf) {
    int b = blockIdx.x;
    int t = threadIdx.x;
    if (b < 256) {
        __shared__ float tile[32][33];
        int bx = b & 15, by = b >> 4;
        int tx = t & 31, ty = t >> 5;   // 32 x 8
        for (int i = ty; i < 32; i += 8)
            tile[i][tx] = w[(by * 32 + i) * D + bx * 32 + tx];
        __syncthreads();
        for (int i = ty; i < 32; i += 8)
            wt[(bx * 32 + i) * D + by * 32 + tx] = __float2bfloat16(tile[tx][i]);
        return;
    }
    // scatter: thread handles nnz i0 and i1 (coalesced); atomics issued together,
    // dependent stores issued together -> two latency chains overlap.
    int base = (b - 256) * 512;
    int i0 = base + t, i1 = base + 256 + t;
    bool g0 = i0 < nnz, g1 = i1 < nnz;
    int r0 = 0, c0 = 0, r1 = 0, c1 = 0;
    float v0 = 0.f, v1 = 0.f;
    if (g0) { r0 = rows[i0]; c0 = cols[i0]; v0 = vals[i0]; }
    if (g1) { r1 = rows[i1]; c1 = cols[i1]; v1 = vals[i1]; }
    int p0 = g0 ? atomicAdd(&counts[r0], 1) : 0;
    int p1 = g1 ? atomicAdd(&counts[r1], 1) : 0;
    if (g0) {
        if (p0 < CAP) {
            bucket[(size_t)r0 * CAP + p0] = make_uint2((unsigned)c0, __float_as_uint(v0));
        } else {
            int o = atomicAdd(ovf_cnt, 1);
            if (o < OVFCAP) ovf[o] = make_uint4((unsigned)r0, (unsigned)c0, __float_as_uint(v0), 0u);
        }
    }
    if (g1) {
        if (p1 < CAP) {
            bucket[(size_t)r1 * CAP + p1] = make_uint2((unsigned)c1, __float_as_uint(v1));
        } else {
            int o = atomicAdd(ovf_cnt, 1);
            if (o < OVFCAP) ovf[o] = make_uint4((unsigned)r1, (unsigned)c1, __float_as_uint(v1), 0u);
        }
    }
}

// ---------- main compute: one wave per TWO rows (2 independent gather+FMA chains) ----------
__global__ __launch_bounds__(256, 6) void k_spmm(const int* __restrict__ counts,
                                                 const uint2* __restrict__ bucket,
                                                 const uint4* __restrict__ wt4,  // bf16 wT, 64 uint4/row
                                                 const f32x4* __restrict__ bias4,
                                                 f32x4* __restrict__ out,
                                                 const int* __restrict__ ovf_cnt,
                                                 const uint4* __restrict__ ovf) {
    int wv = (int)((blockIdx.x * blockDim.x + threadIdx.x) >> 6);   // wave id = row pair
    int lane = threadIdx.x & 63;
    int rA = wv * 2, rB = rA + 1;
    f32x4 bb0 = bias4[lane * 2];
    f32x4 bb1 = bias4[lane * 2 + 1];
    f32x4 a0 = bb0, a1 = bb1;    // row A accumulators
    f32x4 b0 = bb0, b1 = bb1;    // row B accumulators
    int cntA = counts[rA]; if (cntA > CAP) cntA = CAP;
    int cntB = counts[rB]; if (cntB > CAP) cntB = CAP;
    int novf = *ovf_cnt;
    // ONE coalesced 512B load covers both rows' pair lists:
    // lanes 0..31 = row A pairs 0..31, lanes 32..63 = row B pairs 0..31 (CAP=32).
    uint2 mypair = bucket[(size_t)rA * CAP + lane];
    int mx = cntA > cntB ? cntA : cntB;
    for (int s = 0; s < mx; ++s) {
        if (s < cntA) {                                  // wave-uniform branch
            unsigned c = (unsigned)__shfl((int)mypair.x, s);
            float v = __uint_as_float(__shfl((int)mypair.y, s));
            uint4 wb = wt4[(size_t)c * 64 + lane];
            f32x4 w0, w1;
            w0.x = __uint_as_float(wb.x << 16);
            w0.y = __uint_as_float(wb.x & 0xffff0000u);
            w0.z = __uint_as_float(wb.y << 16);
            w0.w = __uint_as_float(wb.y & 0xffff0000u);
            w1.x = __uint_as_float(wb.z << 16);
            w1.y = __uint_as_float(wb.z & 0xffff0000u);
            w1.z = __uint_as_float(wb.w << 16);
            w1.w = __uint_as_float(wb.w & 0xffff0000u);
            a0 += v * w0;
            a1 += v * w1;
        }
        if (s < cntB) {                                  // wave-uniform branch
            unsigned c = (unsigned)__shfl((int)mypair.x, 32 + s);
            float v = __uint_as_float(__shfl((int)mypair.y, 32 + s));
            uint4 wb = wt4[(size_t)c * 64 + lane];
            f32x4 w0, w1;
            w0.x = __uint_as_float(wb.x << 16);
            w0.y = __uint_as_float(wb.x & 0xffff0000u);
            w0.z = __uint_as_float(wb.y << 16);
            w0.w = __uint_as_float(wb.y & 0xffff0000u);
            w1.x = __uint_as_float(wb.z << 16);
            w1.y = __uint_as_float(wb.z & 0xffff0000u);
            w1.z = __uint_as_float(wb.w << 16);
            w1.w = __uint_as_float(wb.w & 0xffff0000u);
            b0 += v * w0;
            b1 += v * w1;
        }
    }
    if (novf > 0) {                                      // rare spill path
        if (novf > OVFCAP) novf = OVFCAP;
        for (int e = 0; e < novf; ++e) {
            uint4 p = ovf[e];
            if ((int)p.x == rA || (int)p.x == rB) {
                float v = __uint_as_float(p.z);
                uint4 wb = wt4[(size_t)p.y * 64 + lane];
                f32x4 w0, w1;
                w0.x = __uint_as_float(wb.x << 16);
                w0.y = __uint_as_float(wb.x & 0xffff0000u);
                w0.z = __uint_as_float(wb.y << 16);
                w0.w = __uint_as_float(wb.y & 0xffff0000u);
                w1.x = __uint_as_float(wb.z << 16);
                w1.y = __uint_as_float(wb.z & 0xffff0000u);
                w1.z = __uint_as_float(wb.w << 16);
                w1.w = __uint_as_float(wb.w & 0xffff0000u);
                if ((int)p.x == rA) { a0 += v * w0; a1 += v * w1; }
                else                { b0 += v * w0; b1 += v * w1; }
            }
        }
    }
    f32x4* opA = out + (size_t)rA * (D / 4);
    opA[lane * 2]     = a0;
    opA[lane * 2 + 1] = a1;
    f32x4* opB = out + (size_t)rB * (D / 4);
    opB[lane * 2]     = b0;
    opB[lane * 2 + 1] = b1;
}

// ---------- fallback path (tiny workspace) ----------
__global__ void k_init_bias(const float* __restrict__ bias, float* __restrict__ out, int total) {
    int i = blockIdx.x * blockDim.x + threadIdx.x;
    if (i < total) out[i] = bias[i & (D - 1)];
}

__global__ void k_atomic_spmm(const int* __restrict__ rows, const int* __restrict__ cols,
                              const float* __restrict__ vals, int nnz,
                              const float* __restrict__ w, float* __restrict__ out) {
    int wid = (int)((blockIdx.x * blockDim.x + threadIdx.x) >> 6);
    if (wid >= nnz) return;
    int lane = threadIdx.x & 63;
    int r = rows[wid];
    int c = cols[wid];
    float v = vals[wid];
    float* op = out + (size_t)r * D + lane * 8;
#pragma unroll
    for (int k = 0; k < 8; ++k) {
        float wv = w[(size_t)(lane * 8 + k) * D + c];
        atomicAdd(&op[k], v * wv);
    }
}

extern "C" void kernel_launch(void* const* d_in, const int* in_sizes, int n_in,
                              void* d_out, int out_size, void* d_ws, size_t ws_size,
                              hipStream_t stream) {
    const int*   rows   = (const int*)d_in[0];
    const int*   cols   = (const int*)d_in[1];
    const float* vals   = (const float*)d_in[2];
    const float* weight = (const float*)d_in[3];
    const float* bias   = (const float*)d_in[4];
    float*       out    = (float*)d_out;
    const int nnz = in_sizes[0];

    // workspace carve-out
    char* ws = (char*)d_ws;
    size_t off = 0;
    auto alloc = [&](size_t bytes) -> void* {
        off = (off + 255) & ~(size_t)255;
        void* p = ws + off;
        off += bytes;
        return p;
    };
    __hip_bfloat16* wT = (__hip_bfloat16*)alloc((size_t)D * D * sizeof(__hip_bfloat16)); // 512 KiB
    int*   counts  = (int*)  alloc((size_t)NROWS * sizeof(int));                // 256 KiB
    int*   ovf_cnt = (int*)  alloc(256);                                        // 1 int
    uint4* ovf     = (uint4*)alloc((size_t)OVFCAP * sizeof(uint4));             // 64 KiB
    uint2* bucket  = (uint2*)alloc((size_t)NROWS * CAP * sizeof(uint2));        // 16 MiB
    const size_t need_full = off;

    if (need_full <= ws_size) {
        // ---- 3 dispatches ----
        const int scatterBlocks = (nnz + 511) / 512;
        k_zero<<<NROWS / 1024, 256, 0, stream>>>(counts, ovf_cnt);
        k_bucket<<<256 + scatterBlocks, 256, 0, stream>>>(weight, wT, rows, cols, vals, nnz,
                                                          counts, bucket, ovf_cnt, ovf);
        k_spmm<<<NROWS / 8, 256, 0, stream>>>(counts, bucket, (const uint4*)wT,
                                              (const f32x4*)bias, (f32x4*)out, ovf_cnt, ovf);
    } else {
        // ---- atomic fallback ----
        k_init_bias<<<(out_size + 255) / 256, 256, 0, stream>>>(bias, out, out_size);
        k_atomic_spmm<<<((size_t)nnz * 64 + 255) / 256, 256, 0, stream>>>(rows, cols, vals, nnz, weight, out);
    }
}

// Round 11
// 78.550 us; speedup vs baseline: 6.5520x; 1.1041x over previous
//
#include <hip/hip_runtime.h>
#include <hip/hip_bf16.h>

#define D 512            // d_in == d_out == 512
#define NROWS 65536      // output rows
#define CAP 32           // per-row bucket capacity (Poisson mean 8; P(>32) ~ 1e-10)
#define OVFCAP 4096      // overflow spill capacity

typedef float f32x4 __attribute__((ext_vector_type(4)));
typedef int   i32x4 __attribute__((ext_vector_type(4)));

// ---------- zero counts + ovf_cnt ----------
__global__ __launch_bounds__(256) void k_zero(int* __restrict__ counts,
                                              int* __restrict__ ovf_cnt) {
    int i = blockIdx.x * 256 + threadIdx.x;
    i32x4 z = {0, 0, 0, 0};
    ((i32x4*)counts)[i] = z;
    if (i == 0) *ovf_cnt = 0;
}

// ---------- fused: transpose w -> bf16 wT (blocks 0..255) + bucket scatter (1 nnz/thread) ----------
__global__ __launch_bounds__(256) void k_bucket(const float* __restrict__ w,
                                                __hip_bfloat16* __restrict__ wt,
                                                const int* __restrict__ rows,
                                                const int* __restrict__ cols,
                                                const float* __restrict__ vals, int nnz,
                                                int* __restrict__ counts, uint2* __restrict__ bucket,
                                                int* __restrict__ ovf_cnt, uint4* __restrict__ ovf) {
    int b = blockIdx.x;
    int t = threadIdx.x;
    if (b < 256) {
        __shared__ float tile[32][33];
        int bx = b & 15, by = b >> 4;
        int tx = t & 31, ty = t >> 5;   // 32 x 8
        for (int i = ty; i < 32; i += 8)
            tile[i][tx] = w[(by * 32 + i) * D + bx * 32 + tx];
        __syncthreads();
        for (int i = ty; i < 32; i += 8)
            wt[(bx * 32 + i) * D + by * 32 + tx] = __float2bfloat16(tile[tx][i]);
        return;
    }
    int i = (b - 256) * 256 + t;        // 1 nnz per thread (R7 form — best measured)
    if (i >= nnz) return;
    int r = rows[i];
    int c = cols[i];
    float v = vals[i];
    int pos = atomicAdd(&counts[r], 1);
    if (pos < CAP) {
        bucket[(size_t)r * CAP + pos] = make_uint2((unsigned)c, __float_as_uint(v));
    } else {
        int o = atomicAdd(ovf_cnt, 1);
        if (o < OVFCAP)
            ovf[o] = make_uint4((unsigned)r, (unsigned)c, __float_as_uint(v), 0u);
    }
}

// unpack one bf16x8 gather and accumulate: 8 VALU unpack + 8 FMA
#define ACC8(wb, vv)                                   \
    do {                                               \
        f32x4 w0, w1;                                  \
        w0.x = __uint_as_float((wb).x << 16);          \
        w0.y = __uint_as_float((wb).x & 0xffff0000u);  \
        w0.z = __uint_as_float((wb).y << 16);          \
        w0.w = __uint_as_float((wb).y & 0xffff0000u);  \
        w1.x = __uint_as_float((wb).z << 16);          \
        w1.y = __uint_as_float((wb).z & 0xffff0000u);  \
        w1.z = __uint_as_float((wb).w << 16);          \
        w1.w = __uint_as_float((wb).w & 0xffff0000u);  \
        a0 += (vv) * w0;                               \
        a1 += (vv) * w1;                               \
    } while (0)

// ---------- main compute: one wave per row; readlane broadcasts (no LDS pipe);
// ---------- 4 gathers in flight per straight-line batch (progressive vmcnt) ----------
__global__ __launch_bounds__(256) void k_spmm(const int* __restrict__ counts,
                                              const uint2* __restrict__ bucket,
                                              const uint4* __restrict__ wt4,   // bf16 wT, 64 uint4/row
                                              const f32x4* __restrict__ bias4,
                                              f32x4* __restrict__ out,
                                              const int* __restrict__ ovf_cnt,
                                              const uint4* __restrict__ ovf) {
    int wid = (int)((blockIdx.x * blockDim.x + threadIdx.x) >> 6);
    int row = __builtin_amdgcn_readfirstlane(wid);     // SGPR row -> scalar addressing
    int lane = threadIdx.x & 63;
    f32x4 a0 = bias4[lane * 2];
    f32x4 a1 = bias4[lane * 2 + 1];
    int cnt = counts[row];
    int novf = *ovf_cnt;                 // uniformly 0 in practice
    if (cnt > CAP) cnt = CAP;
    // lane s holds pair s; lanes >= cnt hold (0,0) => padded iterations are no-ops
    uint2 mypair = make_uint2(0u, 0u);
    if (lane < cnt) mypair = bucket[(size_t)row * CAP + lane];
    int nb4 = (cnt + 3) >> 2;
    for (int b4 = 0; b4 < nb4; ++b4) {
        int s = b4 << 2;
        unsigned c0 = (unsigned)__builtin_amdgcn_readlane((int)mypair.x, s);
        unsigned c1 = (unsigned)__builtin_amdgcn_readlane((int)mypair.x, s + 1);
        unsigned c2 = (unsigned)__builtin_amdgcn_readlane((int)mypair.x, s + 2);
        unsigned c3 = (unsigned)__builtin_amdgcn_readlane((int)mypair.x, s + 3);
        float v0 = __uint_as_float((unsigned)__builtin_amdgcn_readlane((int)mypair.y, s));
        float v1 = __uint_as_float((unsigned)__builtin_amdgcn_readlane((int)mypair.y, s + 1));
        float v2 = __uint_as_float((unsigned)__builtin_amdgcn_readlane((int)mypair.y, s + 2));
        float v3 = __uint_as_float((unsigned)__builtin_amdgcn_readlane((int)mypair.y, s + 3));
        uint4 wb0 = wt4[(size_t)c0 * 64 + lane];       // 4 independent gathers in flight
        uint4 wb1 = wt4[(size_t)c1 * 64 + lane];
        uint4 wb2 = wt4[(size_t)c2 * 64 + lane];
        uint4 wb3 = wt4[(size_t)c3 * 64 + lane];
        ACC8(wb0, v0);
        ACC8(wb1, v1);
        ACC8(wb2, v2);
        ACC8(wb3, v3);
    }
    if (novf > 0) {                      // rare spill path
        if (novf > OVFCAP) novf = OVFCAP;
        for (int e = 0; e < novf; ++e) {
            uint4 p = ovf[e];
            if ((int)p.x == row) {
                float v = __uint_as_float(p.z);
                uint4 wb = wt4[(size_t)p.y * 64 + lane];
                ACC8(wb, v);
            }
        }
    }
    f32x4* op = out + (size_t)row * (D / 4);
    op[lane * 2]     = a0;
    op[lane * 2 + 1] = a1;
}

// ---------- fallback path (tiny workspace) ----------
__global__ void k_init_bias(const float* __restrict__ bias, float* __restrict__ out, int total) {
    int i = blockIdx.x * blockDim.x + threadIdx.x;
    if (i < total) out[i] = bias[i & (D - 1)];
}

__global__ void k_atomic_spmm(const int* __restrict__ rows, const int* __restrict__ cols,
                              const float* __restrict__ vals, int nnz,
                              const float* __restrict__ w, float* __restrict__ out) {
    int wid = (int)((blockIdx.x * blockDim.x + threadIdx.x) >> 6);
    if (wid >= nnz) return;
    int lane = threadIdx.x & 63;
    int r = rows[wid];
    int c = cols[wid];
    float v = vals[wid];
    float* op = out + (size_t)r * D + lane * 8;
#pragma unroll
    for (int k = 0; k < 8; ++k) {
        float wv = w[(size_t)(lane * 8 + k) * D + c];
        atomicAdd(&op[k], v * wv);
    }
}

extern "C" void kernel_launch(void* const* d_in, const int* in_sizes, int n_in,
                              void* d_out, int out_size, void* d_ws, size_t ws_size,
                              hipStream_t stream) {
    const int*   rows   = (const int*)d_in[0];
    const int*   cols   = (const int*)d_in[1];
    const float* vals   = (const float*)d_in[2];
    const float* weight = (const float*)d_in[3];
    const float* bias   = (const float*)d_in[4];
    float*       out    = (float*)d_out;
    const int nnz = in_sizes[0];

    // workspace carve-out
    char* ws = (char*)d_ws;
    size_t off = 0;
    auto alloc = [&](size_t bytes) -> void* {
        off = (off + 255) & ~(size_t)255;
        void* p = ws + off;
        off += bytes;
        return p;
    };
    __hip_bfloat16* wT = (__hip_bfloat16*)alloc((size_t)D * D * sizeof(__hip_bfloat16)); // 512 KiB
    int*   counts  = (int*)  alloc((size_t)NROWS * sizeof(int));                // 256 KiB
    int*   ovf_cnt = (int*)  alloc(256);                                        // 1 int
    uint4* ovf     = (uint4*)alloc((size_t)OVFCAP * sizeof(uint4));             // 64 KiB
    uint2* bucket  = (uint2*)alloc((size_t)NROWS * CAP * sizeof(uint2));        // 16 MiB
    const size_t need_full = off;

    if (need_full <= ws_size) {
        // ---- 3 dispatches (R7 pipeline, new spmm inner loop) ----
        const int nnzBlocks = (nnz + 255) / 256;
        k_zero<<<NROWS / 1024, 256, 0, stream>>>(counts, ovf_cnt);
        k_bucket<<<256 + nnzBlocks, 256, 0, stream>>>(weight, wT, rows, cols, vals, nnz,
                                                      counts, bucket, ovf_cnt, ovf);
        k_spmm<<<NROWS / 4, 256, 0, stream>>>(counts, bucket, (const uint4*)wT,
                                              (const f32x4*)bias, (f32x4*)out, ovf_cnt, ovf);
    } else {
        // ---- atomic fallback ----
        k_init_bias<<<(out_size + 255) / 256, 256, 0, stream>>>(bias, out, out_size);
        k_atomic_spmm<<<((size_t)nnz * 64 + 255) / 256, 256, 0, stream>>>(rows, cols, vals, nnz, weight, out);
    }
}